// Round 12
// baseline (426.158 us; speedup 1.0000x reference)
//
#include <hip/hip_runtime.h>
#include <hip/hip_fp16.h>
#include <math.h>

#define N_POL 20000
#define N_COMP 80000
#define NN (N_POL + N_COMP)
#define EE 1000000
#define NB1 ((NN + 1023) / 1024)  // scan blocks = 98
#define LOG2E 1.44269504f
#define GB1 ((NN + 127) / 128)  // gemm1 blocks = 782
#define SB ((EE + 255) / 256)   // scatter/hist blocks = 3907
#define AB 3125                 // al blocks (32 nodes each)
#define PB 349                  // prep blocks

typedef short bf16x8 __attribute__((ext_vector_type(8)));
typedef float f32x4 __attribute__((ext_vector_type(4)));

// 32B interleaved permuted-edge record: 1 line touch per scatter
struct __align__(16) PEdge {
  int s;                 // src node
  float ale2;            // (ea . V2) * log2e
  unsigned short a1[8];  // fp16 (ea . V1[:,h]) * log2e
  unsigned pad[2];
};

// ---------- helpers ----------
__device__ __forceinline__ float wave_sum(float v) {
#pragma unroll
  for (int o = 32; o > 0; o >>= 1) v += __shfl_xor(v, o);
  return v;
}
__device__ __forceinline__ float wave_max(float v) {
#pragma unroll
  for (int o = 32; o > 0; o >>= 1) v = fmaxf(v, __shfl_xor(v, o));
  return v;
}
__device__ __forceinline__ unsigned short f2bf(float f) {
  unsigned b = __float_as_uint(f);
  return (unsigned short)((b + 0x7FFFu + ((b >> 16) & 1u)) >> 16);
}
__device__ __forceinline__ float bf2f(unsigned short u) {
  return __uint_as_float(((unsigned)u) << 16);
}
__device__ __forceinline__ unsigned short f2h(float f) {
  __half h = __float2half_rn(f);
  return *(unsigned short*)&h;
}
__device__ __forceinline__ float h2f(unsigned short u) {
  __half h = *(__half*)&u;
  return __half2float(h);
}

// ---------- F1: prep (transposes + tables + logit vectors + ws1hT/wd1hT) ∥ hist ----------
__global__ __launch_bounds__(256) void k_fuse1(
    const float* W1, const float* W2, const float* as2, const float* ad2,
    const float* We1, const float* ae1, const float* We2, const float* ae2,
    const float* sector_emb, const float* industry_emb, const float* Wc,
    const float* as1, const float* ad1, const int* dst, unsigned short* W1t,
    unsigned short* W2t, float* Ts, float* Ti, float* us2, float* ud2, float* V1,
    float* V2, float* ws1hT, float* wd1hT, unsigned* hist) {
  int bid = blockIdx.x;
  if (bid >= PB) {  // hist role
    int e = (bid - PB) * 256 + threadIdx.x;
    if (e < EE) atomicAdd(&hist[dst[e]], 1u);
    return;
  }
  int id = bid * 256 + threadIdx.x;
  if (id < 32768) {  // W1t [256][128]
    int n = id >> 7, k = id & 127;
    W1t[id] = f2bf(W1[k * 256 + n]);
  } else if (id < 65536) {  // W2t [128][256]
    int id2 = id - 32768;
    int n = id2 >> 8, k = id2 & 255;
    W2t[id2] = f2bf(W2[k * 128 + n]);
  } else if (id < 67584) {  // Ts [16][128]
    int id2 = id - 65536;
    int n = id2 >> 7, c = id2 & 127;
    float a = 0.f;
#pragma unroll
    for (int k = 0; k < 8; k++) a = fmaf(sector_emb[n * 8 + k], Wc[k * 128 + c], a);
    Ts[id2] = a;
  } else if (id < 86784) {  // Ti [150][128]
    int id2 = id - 67584;
    int n = id2 >> 7, c = id2 & 127;
    float a = 0.f;
#pragma unroll
    for (int k = 0; k < 8; k++) a = fmaf(industry_emb[n * 8 + k], Wc[(8 + k) * 128 + c], a);
    Ti[id2] = a;
  } else if (id < 87040) {  // us2/ud2 [256] (x log2e)
    int t = id - 86784;
    float s = 0.f, d = 0.f;
    for (int c = 0; c < 128; c++) {
      float w = W2[t * 128 + c];
      s = fmaf(w, as2[c], s);
      d = fmaf(w, ad2[c], d);
    }
    us2[t] = s * LOG2E;
    ud2[t] = d * LOG2E;
  } else if (id < 87104) {  // V1 [5][8] (x log2e)
    int t = id - 87040;
    int k = t >> 3, h = t & 7;
    if (k < 5) {
      float v = 0.f;
      for (int c = 0; c < 32; c++) v = fmaf(We1[k * 256 + h * 32 + c], ae1[h * 32 + c], v);
      V1[k * 8 + h] = v * LOG2E;
    }
  } else if (id < 87109) {  // V2 [5] (x log2e)
    int t = id - 87104;
    float v = 0.f;
    for (int c = 0; c < 128; c++) v = fmaf(We2[t * 128 + c], ae2[c], v);
    V2[t] = v * LOG2E;
  } else if (id < 89157) {  // ws1hT/wd1hT [8][128] (x log2e)
    int t2 = id - 87109;
    int issd = t2 >> 10;
    int r = t2 & 1023;
    int k = r & 127, h = r >> 7;
    const float* a = issd ? ad1 : as1;
    float v = 0.f;
#pragma unroll
    for (int c = 0; c < 32; c++) v = fmaf(W1[k * 256 + h * 32 + c], a[h * 32 + c], v);
    if (issd) wd1hT[h * 128 + k] = v * LOG2E;
    else ws1hT[h * 128 + k] = v * LOG2E;
  }
}

// ---------- F_ES: scan1(256-thread) ∥ encode ----------
__global__ __launch_bounds__(256) void k_fuse_es(
    const unsigned* hist, unsigned* rowptr, unsigned* part, const float* pol_feat,
    const int* state_ids, const int* comp_cat, const float* comp_price,
    const float* Wp, const float* bp, const float* state_emb, const float* Ts,
    const float* Ti, const float* Wc, const float* bc, const float* ln_g,
    const float* ln_b, unsigned short* x) {
  int t = threadIdx.x;
  int bid = blockIdx.x;
  if (bid < NB1) {  // ---- scan role: 1024 hist entries per block ----
    int lane = t & 63, wid = t >> 6;
    int base = bid * 1024 + t * 4;
    unsigned v0 = (base + 0 < NN) ? hist[base + 0] : 0u;
    unsigned v1 = (base + 1 < NN) ? hist[base + 1] : 0u;
    unsigned v2 = (base + 2 < NN) ? hist[base + 2] : 0u;
    unsigned v3 = (base + 3 < NN) ? hist[base + 3] : 0u;
    unsigned s0 = v0, s1 = s0 + v1, s2 = s1 + v2, s3 = s2 + v3;
    unsigned inc = s3;
#pragma unroll
    for (int o = 1; o < 64; o <<= 1) {
      unsigned n = __shfl_up(inc, o);
      if (lane >= o) inc += n;
    }
    __shared__ unsigned wt[4];
    if (lane == 63) wt[wid] = inc;
    __syncthreads();
    unsigned woff = 0;
    for (int ww = 0; ww < wid; ww++) woff += wt[ww];
    unsigned exc = woff + inc - s3;
    if (base + 0 < NN) rowptr[base + 0] = exc;
    if (base + 1 < NN) rowptr[base + 1] = exc + s0;
    if (base + 2 < NN) rowptr[base + 2] = exc + s1;
    if (base + 3 < NN) rowptr[base + 3] = exc + s2;
    if (t == 255) part[bid] = woff + inc;
    return;
  }
  // ---- encode role: 2 nodes per block ----
  int eb = bid - NB1;
  int i = eb * 2 + (t >> 7), c = t & 127;
  float v;
  if (i < N_POL) {
    float acc = bp[c];
#pragma unroll
    for (int k = 0; k < 7; k++) acc = fmaf(pol_feat[i * 7 + k], Wp[k * 128 + c], acc);
    v = fmaxf(acc, 0.f) + state_emb[state_ids[i] * 128 + c];
  } else {
    int j = i - N_POL;
    int sc = comp_cat[2 * j], in = comp_cat[2 * j + 1];
    float acc = Ts[sc * 128 + c] + Ti[in * 128 + c] +
                comp_price[j] * Wc[16 * 128 + c] + bc[c];
    v = fmaxf(acc, 0.f);
  }
  __shared__ float red[4];
  int wid = t >> 6, lane = t & 63;
  int base = (t >> 7) << 1;
  float s = wave_sum(v);
  if (lane == 0) red[wid] = s;
  __syncthreads();
  float mu = (red[base] + red[base + 1]) * (1.f / 128.f);
  float t0 = v - mu;
  __syncthreads();
  float s2 = wave_sum(t0 * t0);
  if (lane == 0) red[wid] = s2;
  __syncthreads();
  float var = (red[base] + red[base + 1]) * (1.f / 128.f);
  float r = rsqrtf(var + 1e-5f);
  float xf = t0 * r * ln_g[c] + ln_b[c];
  x[(size_t)i * 128 + c] = f2bf(xf);
}

// scan3 with inline part-prefix
__global__ __launch_bounds__(256) void k_scan3(unsigned* rowptr, const unsigned* part,
                                               unsigned* cursor) {
  __shared__ unsigned pref[128];
  int t = threadIdx.x;
  unsigned orig = 0u;
  if (t < 128) {
    orig = (t < NB1) ? part[t] : 0u;
    pref[t] = orig;
  }
  __syncthreads();
  for (int o = 1; o < 128; o <<= 1) {
    unsigned add = 0u;
    if (t < 128 && t >= o) add = pref[t - o];
    __syncthreads();
    if (t < 128) pref[t] += add;
    __syncthreads();
  }
  if (t < 128) pref[t] -= orig;  // exclusive
  __syncthreads();
  int i = blockIdx.x * 256 + t;
  if (i < NN) {
    unsigned r = rowptr[i] + pref[i >> 10];
    rowptr[i] = r;
    cursor[i] = r;
  }
  if (i == 0) rowptr[NN] = EE;
}

// ---------- F2: gemm1 (MFMA) ∥ scatter (32B PEdge) ∥ al (x·ws1hT), role-interleaved ----------
__global__ __launch_bounds__(256) void k_fuse2(
    const unsigned short* x, const unsigned short* W1t, unsigned short* xw1,
    const int* src, const int* dst, const float* ea, const float* V1, const float* V2,
    unsigned* cursor, PEdge* ep, const float* ws1hT, const float* wd1hT,
    float* al_s1, float* al_d1) {
  __shared__ char wlds[65536];
  int bid = blockIdx.x;
  bool isg = (bid % 9 == 0) && (bid / 9 < GB1);
  if (isg) {  // ---- gemm1 role ----
    int gb = bid / 9;
    int tid = threadIdx.x;
#pragma unroll
    for (int it = 0; it < 16; it++) {
      int cch = it * 256 + tid;
      int row = cch >> 4, seg = cch & 15;
      uint4 v = *(const uint4*)(W1t + row * 128 + seg * 8);
      *(uint4*)(&wlds[(row * 256 + seg * 16) ^ ((row & 7) << 4)]) = v;
    }
    __syncthreads();
    int wid = tid >> 6, l = tid & 63;
    int cl = l & 15, kh = l >> 4;
    int swz = (cl & 7) << 4;
    long r0 = (long)gb * 128 + wid * 32;
    f32x4 acc[2][16];
#pragma unroll
    for (int rt = 0; rt < 2; rt++)
#pragma unroll
      for (int nt = 0; nt < 16; nt++) acc[rt][nt] = {0.f, 0.f, 0.f, 0.f};
    long ra0 = r0 + cl; if (ra0 > NN - 1) ra0 = NN - 1;
    long ra1 = r0 + 16 + cl; if (ra1 > NN - 1) ra1 = NN - 1;
#pragma unroll
    for (int kk = 0; kk < 4; kk++) {
      bf16x8 a0 = *(const bf16x8*)(x + ra0 * 128 + kk * 32 + kh * 8);
      bf16x8 a1 = *(const bf16x8*)(x + ra1 * 128 + kk * 32 + kh * 8);
#pragma unroll
      for (int nt = 0; nt < 16; nt++) {
        bf16x8 b = *(const bf16x8*)(&wlds[(((nt * 16 + cl) * 256) + kk * 64 + kh * 16) ^ swz]);
        acc[0][nt] = __builtin_amdgcn_mfma_f32_16x16x32_bf16(a0, b, acc[0][nt], 0, 0, 0);
        acc[1][nt] = __builtin_amdgcn_mfma_f32_16x16x32_bf16(a1, b, acc[1][nt], 0, 0, 0);
      }
    }
#pragma unroll
    for (int rt = 0; rt < 2; rt++)
#pragma unroll
      for (int nt = 0; nt < 16; nt++)
#pragma unroll
        for (int j = 0; j < 4; j++) {
          long row = r0 + rt * 16 + kh * 4 + j;
          if (row < NN) xw1[row * 256 + nt * 16 + cl] = f2bf(acc[rt][nt][j]);
        }
    return;
  }
  int j = bid - ((bid + 8) / 9 < GB1 ? (bid + 8) / 9 : GB1);
  if (j < SB) {  // ---- scatter role ----
    int e = j * 256 + threadIdx.x;
    if (e >= EE) return;
    int d = dst[e];
    unsigned pos = atomicAdd(&cursor[d], 1u);
    float av[5];
#pragma unroll
    for (int k = 0; k < 5; k++) av[k] = ea[(size_t)e * 5 + k];
    float a2 = 0.f;
#pragma unroll
    for (int k = 0; k < 5; k++) a2 = fmaf(av[k], V2[k], a2);
    unsigned short hb[8];
#pragma unroll
    for (int hh = 0; hh < 8; hh++) {
      float a1 = 0.f;
#pragma unroll
      for (int k = 0; k < 5; k++) a1 = fmaf(av[k], V1[k * 8 + hh], a1);
      hb[hh] = f2h(a1);
    }
    uint4 w0, w1;
    w0.x = (unsigned)src[e];
    w0.y = __float_as_uint(a2);
    w0.z = (unsigned)hb[0] | ((unsigned)hb[1] << 16);
    w0.w = (unsigned)hb[2] | ((unsigned)hb[3] << 16);
    w1.x = (unsigned)hb[4] | ((unsigned)hb[5] << 16);
    w1.y = (unsigned)hb[6] | ((unsigned)hb[7] << 16);
    w1.z = 0u; w1.w = 0u;
    uint4* p = (uint4*)(ep + pos);
    p[0] = w0;
    p[1] = w1;
  } else {  // ---- al role: al_s1/al_d1 = x . ws1hT/wd1hT (32 nodes/block) ----
    int ab = j - SB;  // [0, AB)
    int lane = threadIdx.x & 63, wid = threadIdx.x >> 6;
    int g = lane >> 3;         // head
    int cb = (lane & 7) * 16;  // channel base
    float wsv[16], wdv[16];
#pragma unroll
    for (int q = 0; q < 4; q++) {
      *(float4*)(wsv + q * 4) = *(const float4*)(ws1hT + g * 128 + cb + q * 4);
      *(float4*)(wdv + q * 4) = *(const float4*)(wd1hT + g * 128 + cb + q * 4);
    }
    int nodebase = ab * 32 + wid * 8;
    for (int nn = 0; nn < 8; nn++) {
      int i = nodebase + nn;
      bf16x8 xa = *(const bf16x8*)(x + (size_t)i * 128 + cb);
      bf16x8 xb = *(const bf16x8*)(x + (size_t)i * 128 + cb + 8);
      float s = 0.f, d = 0.f;
#pragma unroll
      for (int q = 0; q < 8; q++) {
        float xv = bf2f((unsigned short)xa[q]);
        s = fmaf(xv, wsv[q], s);
        d = fmaf(xv, wdv[q], d);
      }
#pragma unroll
      for (int q = 0; q < 8; q++) {
        float xv = bf2f((unsigned short)xb[q]);
        s = fmaf(xv, wsv[8 + q], s);
        d = fmaf(xv, wdv[8 + q], d);
      }
      s += __shfl_xor(s, 1); s += __shfl_xor(s, 2); s += __shfl_xor(s, 4);
      d += __shfl_xor(d, 1); d += __shfl_xor(d, 2); d += __shfl_xor(d, 4);
      if ((lane & 7) == 0) {
        al_s1[i * 8 + g] = s;
        al_d1[i * 8 + g] = d;
      }
    }
  }
}

// ---------- K5: MFMA xw2(bf16) = h(bf16)@W2 [N,128] ----------
__global__ __launch_bounds__(256) void k_gemm2(const unsigned short* h,
                                               const unsigned short* W2t,
                                               unsigned short* xw2) {
  __shared__ char wlds[65536];
  int tid = threadIdx.x;
#pragma unroll
  for (int it = 0; it < 16; it++) {
    int cch = it * 256 + tid;
    int row = cch >> 5, seg = cch & 31;
    uint4 v = *(const uint4*)(W2t + row * 256 + seg * 8);
    *(uint4*)(&wlds[(row * 512 + seg * 16) ^ ((row & 7) << 4)]) = v;
  }
  __syncthreads();
  int wid = tid >> 6, l = tid & 63;
  int cl = l & 15, kh = l >> 4;
  int swz = (cl & 7) << 4;
  long r0 = (long)blockIdx.x * 128 + wid * 32;
  f32x4 acc[2][8];
#pragma unroll
  for (int rt = 0; rt < 2; rt++)
#pragma unroll
    for (int nt = 0; nt < 8; nt++) acc[rt][nt] = {0.f, 0.f, 0.f, 0.f};
  long ra0 = r0 + cl; if (ra0 > NN - 1) ra0 = NN - 1;
  long ra1 = r0 + 16 + cl; if (ra1 > NN - 1) ra1 = NN - 1;
#pragma unroll
  for (int kk = 0; kk < 8; kk++) {
    bf16x8 a0 = *(const bf16x8*)(h + ra0 * 256 + kk * 32 + kh * 8);
    bf16x8 a1 = *(const bf16x8*)(h + ra1 * 256 + kk * 32 + kh * 8);
#pragma unroll
    for (int nt = 0; nt < 8; nt++) {
      bf16x8 b = *(const bf16x8*)(&wlds[(((nt * 16 + cl) * 512) + kk * 64 + kh * 16) ^ swz]);
      acc[0][nt] = __builtin_amdgcn_mfma_f32_16x16x32_bf16(a0, b, acc[0][nt], 0, 0, 0);
      acc[1][nt] = __builtin_amdgcn_mfma_f32_16x16x32_bf16(a1, b, acc[1][nt], 0, 0, 0);
    }
  }
#pragma unroll
  for (int rt = 0; rt < 2; rt++)
#pragma unroll
    for (int nt = 0; nt < 8; nt++)
#pragma unroll
      for (int j = 0; j < 4; j++) {
        long row = r0 + rt * 16 + kh * 4 + j;
        if (row < NN) xw2[row * 128 + nt * 16 + cl] = f2bf(acc[rt][nt][j]);
      }
}

// ---------- K4: layer-1 GAT, wave per dst node, 16-edge double-chunk softmax ----------
__global__ __launch_bounds__(256) void k_gat1(
    const unsigned* rowptr, const PEdge* ep, const float* al_s1, const float* al_d1,
    const unsigned short* xw1, const float* b1, const float* us2, const float* ud2,
    unsigned short* h, float* al_s2, float* al_d2) {
  int w = threadIdx.x >> 6, lane = threadIdx.x & 63;
  int i = blockIdx.x * 4 + w;
  if (i >= NN) return;
  int r0 = rowptr[i], r1 = rowptr[i + 1];
  int hh = lane & 7;   // head (pass A)
  int js = lane >> 3;  // edge-sub (pass A)
  int ah = lane >> 3;  // head owning channels lane*4..lane*4+3 (pass B)
  float ald = al_d1[i * 8 + hh];
  float m = -1e30f, l = 0.f;
  float a0 = 0.f, a1 = 0.f, a2 = 0.f, a3 = 0.f;
  float alesum = 0.f;

  auto chunk16 = [&](int jb) {  // exactly 16 edges
    int jc0 = jb + js, jc1 = jb + 8 + js;
    int s0 = ((const int*)&ep[jc0])[0];
    int s1 = ((const int*)&ep[jc1])[0];
    float e0 = h2f(((const unsigned short*)&ep[jc0])[4 + hh]);
    float e1 = h2f(((const unsigned short*)&ep[jc1])[4 + hh]);
    alesum += e0 + e1;
    float g0 = al_s1[s0 * 8 + hh] + ald + e0;
    g0 = g0 > 0.f ? g0 : 0.2f * g0;
    float g1 = al_s1[s1 * 8 + hh] + ald + e1;
    g1 = g1 > 0.f ? g1 : 0.2f * g1;
    float cm = fmaxf(g0, g1);
    cm = fmaxf(cm, __shfl_xor(cm, 8));
    cm = fmaxf(cm, __shfl_xor(cm, 16));
    cm = fmaxf(cm, __shfl_xor(cm, 32));
    float mn = fmaxf(m, cm);
    float sc = exp2f(m - mn);
    float p0 = exp2f(g0 - mn), p1 = exp2f(g1 - mn);
    float ps = p0 + p1;
    ps += __shfl_xor(ps, 8);
    ps += __shfl_xor(ps, 16);
    ps += __shfl_xor(ps, 32);
    l = l * sc + ps;
    m = mn;
    float asc = __shfl(sc, ah);
    a0 *= asc; a1 *= asc; a2 *= asc; a3 *= asc;
#pragma unroll
    for (int jj = 0; jj < 8; jj++) {
      float pj = __shfl(p0, jj * 8 + ah);
      int sj = __shfl(s0, jj * 8);
      ushort4 xv = ((const ushort4*)(xw1 + (size_t)sj * 256))[lane];
      a0 = fmaf(pj, bf2f(xv.x), a0);
      a1 = fmaf(pj, bf2f(xv.y), a1);
      a2 = fmaf(pj, bf2f(xv.z), a2);
      a3 = fmaf(pj, bf2f(xv.w), a3);
    }
#pragma unroll
    for (int jj = 0; jj < 8; jj++) {
      float pj = __shfl(p1, jj * 8 + ah);
      int sj = __shfl(s1, jj * 8);
      ushort4 xv = ((const ushort4*)(xw1 + (size_t)sj * 256))[lane];
      a0 = fmaf(pj, bf2f(xv.x), a0);
      a1 = fmaf(pj, bf2f(xv.y), a1);
      a2 = fmaf(pj, bf2f(xv.z), a2);
      a3 = fmaf(pj, bf2f(xv.w), a3);
    }
  };

  auto chunk8 = [&](int jb, int cnt) {  // 1..8 edges
    bool valid = js < cnt;
    int jc = jb + (valid ? js : cnt - 1);
    int s = ((const int*)&ep[jc])[0];
    float ale = h2f(((const unsigned short*)&ep[jc])[4 + hh]);
    if (!valid) ale = 0.f;
    alesum += ale;
    float logit = -1e30f;
    if (valid) {
      float al = al_s1[s * 8 + hh] + ald + ale;
      logit = al > 0.f ? al : 0.2f * al;
    }
    float cm = logit;
    cm = fmaxf(cm, __shfl_xor(cm, 8));
    cm = fmaxf(cm, __shfl_xor(cm, 16));
    cm = fmaxf(cm, __shfl_xor(cm, 32));
    float mn = fmaxf(m, cm);
    float sc = exp2f(m - mn);
    float p = exp2f(logit - mn);
    float ps = p;
    ps += __shfl_xor(ps, 8);
    ps += __shfl_xor(ps, 16);
    ps += __shfl_xor(ps, 32);
    l = l * sc + ps;
    m = mn;
    float asc = __shfl(sc, ah);
    a0 *= asc; a1 *= asc; a2 *= asc; a3 *= asc;
    for (int jj = 0; jj < cnt; jj++) {
      float pj = __shfl(p, jj * 8 + ah);
      int sj = __shfl(s, jj * 8);
      ushort4 xv = ((const ushort4*)(xw1 + (size_t)sj * 256))[lane];
      a0 = fmaf(pj, bf2f(xv.x), a0);
      a1 = fmaf(pj, bf2f(xv.y), a1);
      a2 = fmaf(pj, bf2f(xv.z), a2);
      a3 = fmaf(pj, bf2f(xv.w), a3);
    }
  };

  int jb = r0;
  for (; jb + 16 <= r1; jb += 16) chunk16(jb);
  if (jb + 8 <= r1) { chunk8(jb, 8); jb += 8; }
  if (jb < r1) chunk8(jb, r1 - jb);

  // self-loop (edge_attr = mean of incoming per-edge ale, by linearity)
  alesum += __shfl_xor(alesum, 8);
  alesum += __shfl_xor(alesum, 16);
  alesum += __shfl_xor(alesum, 32);
  float inv = 1.f / fmaxf((float)(r1 - r0), 1.f);
  float aleS = alesum * inv;
  {
    float al = al_s1[i * 8 + hh] + ald + aleS;
    float logit = al > 0.f ? al : 0.2f * al;
    float mn = fmaxf(m, logit);
    float sc = exp2f(m - mn);
    float p = exp2f(logit - mn);
    l = l * sc + p;
    m = mn;
    float asc = __shfl(sc, ah);
    float pj = __shfl(p, ah);
    ushort4 xv = ((const ushort4*)(xw1 + (size_t)i * 256))[lane];
    a0 = fmaf(pj, bf2f(xv.x), a0 * asc);
    a1 = fmaf(pj, bf2f(xv.y), a1 * asc);
    a2 = fmaf(pj, bf2f(xv.z), a2 * asc);
    a3 = fmaf(pj, bf2f(xv.w), a3 * asc);
  }
  // finalize: /l + b1, elu
  float lh = __shfl(l, ah);
  float invl = 1.f / (lh + 1e-16f);
  float4 bv = ((const float4*)b1)[lane];
  float v0 = a0 * invl + bv.x, v1 = a1 * invl + bv.y;
  float v2 = a2 * invl + bv.z, v3 = a3 * invl + bv.w;
  v0 = v0 > 0.f ? v0 : expm1f(v0);
  v1 = v1 > 0.f ? v1 : expm1f(v1);
  v2 = v2 > 0.f ? v2 : expm1f(v2);
  v3 = v3 > 0.f ? v3 : expm1f(v3);
  ushort4 hv;
  hv.x = f2bf(v0); hv.y = f2bf(v1); hv.z = f2bf(v2); hv.w = f2bf(v3);
  ((ushort4*)(h + (size_t)i * 256))[lane] = hv;
  // layer-2 logit pieces (us2/ud2 pre-scaled by log2e)
  float4 uv = ((const float4*)us2)[lane];
  float4 dv = ((const float4*)ud2)[lane];
  float ps2 = v0 * uv.x + v1 * uv.y + v2 * uv.z + v3 * uv.w;
  float pd2 = v0 * dv.x + v1 * dv.y + v2 * dv.z + v3 * dv.w;
  ps2 = wave_sum(ps2);
  pd2 = wave_sum(pd2);
  if (lane == 0) { al_s2[i] = ps2; al_d2[i] = pd2; }
}

// ---------- K6: layer-2 GAT, wave per dst node, two-phase softmax (low-VGPR) ----------
__global__ __launch_bounds__(256) void k_gat2(
    const unsigned* rowptr, const PEdge* ep, const float* al_s2, const float* al_d2,
    const unsigned short* xw2, const float* b2, float* out) {
  int w = threadIdx.x >> 6, lane = threadIdx.x & 63;
  int i = blockIdx.x * 4 + w;
  if (i >= NN) return;
  int r0 = rowptr[i], r1 = rowptr[i + 1];
  float ald = al_d2[i];
  float m = -1e30f, l = 0.f, a0 = 0.f, a1 = 0.f;
  float alesum = 0.f;

  auto chunk = [&](int jb, int cnt) {  // 1..64 edges
    bool valid = lane < cnt;
    int jc = jb + (valid ? lane : cnt - 1);
    int2 sv = *(const int2*)&ep[jc];
    int s = sv.x;
    float ale = valid ? __uint_as_float((unsigned)sv.y) : 0.f;
    alesum += ale;
    float logit = -1e30f;
    if (valid) {
      float al = al_s2[s] + ald + ale;
      logit = al > 0.f ? al : 0.2f * al;
    }
    float cm = wave_max(logit);
    float mn = fmaxf(m, cm);
    float sc = exp2f(m - mn);
    float p = exp2f(logit - mn);
    float ps = wave_sum(p);
    l = l * sc + ps;
    m = mn;
    a0 *= sc; a1 *= sc;
    for (int jj = 0; jj < cnt; jj++) {
      float pj = __shfl(p, jj);
      int sj = __shfl(s, jj);
      ushort2 xv = ((const ushort2*)(xw2 + (size_t)sj * 128))[lane];
      a0 = fmaf(pj, bf2f(xv.x), a0);
      a1 = fmaf(pj, bf2f(xv.y), a1);
    }
  };
  int jb = r0;
  for (; jb + 64 <= r1; jb += 64) chunk(jb, 64);
  if (jb < r1) chunk(jb, r1 - jb);

  // self-loop
  alesum = wave_sum(alesum);
  float inv = 1.f / fmaxf((float)(r1 - r0), 1.f);
  float aleS = alesum * inv;
  {
    float al = al_s2[i] + ald + aleS;
    float logit = al > 0.f ? al : 0.2f * al;
    float mn = fmaxf(m, logit);
    float sc = exp2f(m - mn);
    float p = exp2f(logit - mn);
    l = l * sc + p;
    ushort2 xv = ((const ushort2*)(xw2 + (size_t)i * 128))[lane];
    a0 = fmaf(p, bf2f(xv.x), a0 * sc);
    a1 = fmaf(p, bf2f(xv.y), a1 * sc);
  }
  float invl = 1.f / (l + 1e-16f);
  float2 bv = ((const float2*)b2)[lane];
  float2 ov = {a0 * invl + bv.x, a1 * invl + bv.y};
  ((float2*)(out + (size_t)i * 128))[lane] = ov;
}

extern "C" void kernel_launch(void* const* d_in, const int* in_sizes, int n_in,
                              void* d_out, int out_size, void* d_ws, size_t ws_size,
                              hipStream_t stream) {
  const float* pol_feat = (const float*)d_in[0];
  const int* state_ids = (const int*)d_in[1];
  const int* comp_cat = (const int*)d_in[2];
  const float* comp_price = (const float*)d_in[3];
  const int* edge_index = (const int*)d_in[4];
  const float* edge_attr = (const float*)d_in[5];
  const float* Wp = (const float*)d_in[6];
  const float* bp = (const float*)d_in[7];
  const float* state_emb = (const float*)d_in[8];
  const float* sector_emb = (const float*)d_in[9];
  const float* industry_emb = (const float*)d_in[10];
  const float* Wc = (const float*)d_in[11];
  const float* bc = (const float*)d_in[12];
  const float* ln_g = (const float*)d_in[13];
  const float* ln_b = (const float*)d_in[14];
  const float* W1 = (const float*)d_in[15];
  const float* as1 = (const float*)d_in[16];
  const float* ad1 = (const float*)d_in[17];
  const float* We1 = (const float*)d_in[18];
  const float* ae1 = (const float*)d_in[19];
  const float* b1 = (const float*)d_in[20];
  const float* W2 = (const float*)d_in[21];
  const float* as2 = (const float*)d_in[22];
  const float* ad2 = (const float*)d_in[23];
  const float* We2 = (const float*)d_in[24];
  const float* ae2 = (const float*)d_in[25];
  const float* b2 = (const float*)d_in[26];
  const int* srcv = edge_index;
  const int* dstv = edge_index + EE;
  float* out = (float*)d_out;

  // ---- workspace layout (aliased; peak ~143 MiB) ----
  size_t off = 0;
  auto alloc = [&](size_t nbytes) -> char* {
    char* p = (char*)d_ws + off;
    off += ((nbytes + 255) & ~(size_t)255);
    return p;
  };
  // region A: xw1 (bf16, NN*256*2); xw2 (bf16, NN*128*2) reuses it after gat1
  char* regA = alloc((size_t)NN * 512);
  // region B: h (bf16, NN*256*2); x (bf16, NN*128*2) occupies first half (dead after gemm1)
  char* regB = alloc((size_t)NN * 512);
  unsigned short* xw1 = (unsigned short*)regA;
  unsigned short* xw2 = (unsigned short*)regA;
  unsigned short* h = (unsigned short*)regB;
  unsigned short* x = (unsigned short*)regB;
  float* al_s1 = (float*)alloc((size_t)NN * 8 * 4);
  float* al_d1 = (float*)alloc((size_t)NN * 8 * 4);
  float* al_s2 = (float*)alloc((size_t)NN * 4);
  float* al_d2 = (float*)alloc((size_t)NN * 4);
  float* us2 = (float*)alloc(256 * 4);
  float* ud2 = (float*)alloc(256 * 4);
  float* V1 = (float*)alloc(64 * 4);
  float* V2 = (float*)alloc(8 * 4);
  float* Ts = (float*)alloc(16 * 128 * 4);
  float* Ti = (float*)alloc(150 * 128 * 4);
  float* ws1hT = (float*)alloc(1024 * 4);
  float* wd1hT = (float*)alloc(1024 * 4);
  unsigned short* W1t = (unsigned short*)alloc(32768 * 2);
  unsigned short* W2t = (unsigned short*)alloc(32768 * 2);
  unsigned* hist = (unsigned*)alloc((size_t)NN * 4);
  unsigned* rowptr = (unsigned*)alloc((size_t)(NN + 1) * 4);
  unsigned* cursor = (unsigned*)alloc((size_t)NN * 4);
  unsigned* part = (unsigned*)alloc((size_t)NB1 * 4);
  PEdge* ep = (PEdge*)alloc((size_t)EE * sizeof(PEdge));

  hipMemsetAsync(hist, 0, (size_t)NN * 4, stream);

  k_fuse1<<<PB + SB, 256, 0, stream>>>(W1, W2, as2, ad2, We1, ae1, We2, ae2,
                                       sector_emb, industry_emb, Wc, as1, ad1, dstv,
                                       W1t, W2t, Ts, Ti, us2, ud2, V1, V2, ws1hT,
                                       wd1hT, hist);
  k_fuse_es<<<NB1 + NN / 2, 256, 0, stream>>>(hist, rowptr, part, pol_feat, state_ids,
                                              comp_cat, comp_price, Wp, bp, state_emb,
                                              Ts, Ti, Wc, bc, ln_g, ln_b, x);
  k_scan3<<<(NN + 255) / 256, 256, 0, stream>>>(rowptr, part, cursor);
  k_fuse2<<<GB1 + SB + AB, 256, 0, stream>>>(x, W1t, xw1, srcv, dstv, edge_attr, V1,
                                             V2, cursor, ep, ws1hT, wd1hT, al_s1,
                                             al_d1);
  k_gat1<<<NN / 4, 256, 0, stream>>>(rowptr, ep, al_s1, al_d1, xw1, b1, us2, ud2, h,
                                     al_s2, al_d2);
  k_gemm2<<<(NN + 127) / 128, 256, 0, stream>>>(h, W2t, xw2);
  k_gat2<<<NN / 4, 256, 0, stream>>>(rowptr, ep, al_s2, al_d2, xw2, b2, out);
}

// Round 13
// 401.958 us; speedup vs baseline: 1.0602x; 1.0602x over previous
//
#include <hip/hip_runtime.h>
#include <hip/hip_fp16.h>
#include <math.h>

#define N_POL 20000
#define N_COMP 80000
#define NN (N_POL + N_COMP)
#define EE 1000000
#define NB1 ((NN + 1023) / 1024)  // scan blocks = 98
#define LOG2E 1.44269504f
#define GB1 ((NN + 127) / 128)  // gemm1 blocks = 782
#define SB ((EE + 255) / 256)   // scatter/hist blocks = 3907
#define AB 3125                 // al blocks (32 nodes each)
#define S3B ((NN + 255) / 256)  // scan3 blocks = 391
#define PB 349                  // prep blocks

typedef short bf16x8 __attribute__((ext_vector_type(8)));
typedef float f32x4 __attribute__((ext_vector_type(4)));

// 32B interleaved permuted-edge record: 1 line touch per scatter
struct __align__(16) PEdge {
  int s;                 // src node
  float ale2;            // (ea . V2) * log2e
  unsigned short a1[8];  // fp16 (ea . V1[:,h]) * log2e
  unsigned pad[2];
};

// ---------- helpers ----------
__device__ __forceinline__ float wave_sum(float v) {
#pragma unroll
  for (int o = 32; o > 0; o >>= 1) v += __shfl_xor(v, o);
  return v;
}
__device__ __forceinline__ float wave_max(float v) {
#pragma unroll
  for (int o = 32; o > 0; o >>= 1) v = fmaxf(v, __shfl_xor(v, o));
  return v;
}
__device__ __forceinline__ unsigned short f2bf(float f) {
  unsigned b = __float_as_uint(f);
  return (unsigned short)((b + 0x7FFFu + ((b >> 16) & 1u)) >> 16);
}
__device__ __forceinline__ float bf2f(unsigned short u) {
  return __uint_as_float(((unsigned)u) << 16);
}
__device__ __forceinline__ unsigned short f2h(float f) {
  __half h = __float2half_rn(f);
  return *(unsigned short*)&h;
}
__device__ __forceinline__ float h2f(unsigned short u) {
  __half h = *(__half*)&u;
  return __half2float(h);
}

// ---------- F1: prep (transposes + tables + logit vectors + ws1hT/wd1hT) ∥ hist ----------
__global__ __launch_bounds__(256) void k_fuse1(
    const float* W1, const float* W2, const float* as2, const float* ad2,
    const float* We1, const float* ae1, const float* We2, const float* ae2,
    const float* sector_emb, const float* industry_emb, const float* Wc,
    const float* as1, const float* ad1, const int* dst, unsigned short* W1t,
    unsigned short* W2t, float* Ts, float* Ti, float* us2, float* ud2, float* V1,
    float* V2, float* ws1hT, float* wd1hT, unsigned* hist) {
  int bid = blockIdx.x;
  if (bid >= PB) {  // hist role
    int e = (bid - PB) * 256 + threadIdx.x;
    if (e < EE) atomicAdd(&hist[dst[e]], 1u);
    return;
  }
  int id = bid * 256 + threadIdx.x;
  if (id < 32768) {  // W1t [256][128]
    int n = id >> 7, k = id & 127;
    W1t[id] = f2bf(W1[k * 256 + n]);
  } else if (id < 65536) {  // W2t [128][256]
    int id2 = id - 32768;
    int n = id2 >> 8, k = id2 & 255;
    W2t[id2] = f2bf(W2[k * 128 + n]);
  } else if (id < 67584) {  // Ts [16][128]
    int id2 = id - 65536;
    int n = id2 >> 7, c = id2 & 127;
    float a = 0.f;
#pragma unroll
    for (int k = 0; k < 8; k++) a = fmaf(sector_emb[n * 8 + k], Wc[k * 128 + c], a);
    Ts[id2] = a;
  } else if (id < 86784) {  // Ti [150][128]
    int id2 = id - 67584;
    int n = id2 >> 7, c = id2 & 127;
    float a = 0.f;
#pragma unroll
    for (int k = 0; k < 8; k++) a = fmaf(industry_emb[n * 8 + k], Wc[(8 + k) * 128 + c], a);
    Ti[id2] = a;
  } else if (id < 87040) {  // us2/ud2 [256] (x log2e)
    int t = id - 86784;
    float s = 0.f, d = 0.f;
    for (int c = 0; c < 128; c++) {
      float w = W2[t * 128 + c];
      s = fmaf(w, as2[c], s);
      d = fmaf(w, ad2[c], d);
    }
    us2[t] = s * LOG2E;
    ud2[t] = d * LOG2E;
  } else if (id < 87104) {  // V1 [5][8] (x log2e)
    int t = id - 87040;
    int k = t >> 3, h = t & 7;
    if (k < 5) {
      float v = 0.f;
      for (int c = 0; c < 32; c++) v = fmaf(We1[k * 256 + h * 32 + c], ae1[h * 32 + c], v);
      V1[k * 8 + h] = v * LOG2E;
    }
  } else if (id < 87109) {  // V2 [5] (x log2e)
    int t = id - 87104;
    float v = 0.f;
    for (int c = 0; c < 128; c++) v = fmaf(We2[t * 128 + c], ae2[c], v);
    V2[t] = v * LOG2E;
  } else if (id < 89157) {  // ws1hT/wd1hT [8][128] (x log2e)
    int t2 = id - 87109;
    int issd = t2 >> 10;
    int r = t2 & 1023;
    int k = r & 127, h = r >> 7;
    const float* a = issd ? ad1 : as1;
    float v = 0.f;
#pragma unroll
    for (int c = 0; c < 32; c++) v = fmaf(W1[k * 256 + h * 32 + c], a[h * 32 + c], v);
    if (issd) wd1hT[h * 128 + k] = v * LOG2E;
    else ws1hT[h * 128 + k] = v * LOG2E;
  }
}

// ---------- F_ES: scan1(256-thread) ∥ encode ----------
__global__ __launch_bounds__(256) void k_fuse_es(
    const unsigned* hist, unsigned* rowptr, unsigned* part, const float* pol_feat,
    const int* state_ids, const int* comp_cat, const float* comp_price,
    const float* Wp, const float* bp, const float* state_emb, const float* Ts,
    const float* Ti, const float* Wc, const float* bc, const float* ln_g,
    const float* ln_b, unsigned short* x) {
  int t = threadIdx.x;
  int bid = blockIdx.x;
  if (bid < NB1) {  // ---- scan role: 1024 hist entries per block ----
    int lane = t & 63, wid = t >> 6;
    int base = bid * 1024 + t * 4;
    unsigned v0 = (base + 0 < NN) ? hist[base + 0] : 0u;
    unsigned v1 = (base + 1 < NN) ? hist[base + 1] : 0u;
    unsigned v2 = (base + 2 < NN) ? hist[base + 2] : 0u;
    unsigned v3 = (base + 3 < NN) ? hist[base + 3] : 0u;
    unsigned s0 = v0, s1 = s0 + v1, s2 = s1 + v2, s3 = s2 + v3;
    unsigned inc = s3;
#pragma unroll
    for (int o = 1; o < 64; o <<= 1) {
      unsigned n = __shfl_up(inc, o);
      if (lane >= o) inc += n;
    }
    __shared__ unsigned wt[4];
    if (lane == 63) wt[wid] = inc;
    __syncthreads();
    unsigned woff = 0;
    for (int ww = 0; ww < wid; ww++) woff += wt[ww];
    unsigned exc = woff + inc - s3;
    if (base + 0 < NN) rowptr[base + 0] = exc;
    if (base + 1 < NN) rowptr[base + 1] = exc + s0;
    if (base + 2 < NN) rowptr[base + 2] = exc + s1;
    if (base + 3 < NN) rowptr[base + 3] = exc + s2;
    if (t == 255) part[bid] = woff + inc;
    return;
  }
  // ---- encode role: 2 nodes per block ----
  int eb = bid - NB1;
  int i = eb * 2 + (t >> 7), c = t & 127;
  float v;
  if (i < N_POL) {
    float acc = bp[c];
#pragma unroll
    for (int k = 0; k < 7; k++) acc = fmaf(pol_feat[i * 7 + k], Wp[k * 128 + c], acc);
    v = fmaxf(acc, 0.f) + state_emb[state_ids[i] * 128 + c];
  } else {
    int j = i - N_POL;
    int sc = comp_cat[2 * j], in = comp_cat[2 * j + 1];
    float acc = Ts[sc * 128 + c] + Ti[in * 128 + c] +
                comp_price[j] * Wc[16 * 128 + c] + bc[c];
    v = fmaxf(acc, 0.f);
  }
  __shared__ float red[4];
  int wid = t >> 6, lane = t & 63;
  int base = (t >> 7) << 1;
  float s = wave_sum(v);
  if (lane == 0) red[wid] = s;
  __syncthreads();
  float mu = (red[base] + red[base + 1]) * (1.f / 128.f);
  float t0 = v - mu;
  __syncthreads();
  float s2 = wave_sum(t0 * t0);
  if (lane == 0) red[wid] = s2;
  __syncthreads();
  float var = (red[base] + red[base + 1]) * (1.f / 128.f);
  float r = rsqrtf(var + 1e-5f);
  float xf = t0 * r * ln_g[c] + ln_b[c];
  x[(size_t)i * 128 + c] = f2bf(xf);
}

// ---------- scan3 (inline part-prefix) ∥ al (al_s1/al_d1 = x . ws1hT/wd1hT) ----------
__global__ __launch_bounds__(256) void k_scan3_al(
    unsigned* rowptr, const unsigned* part, unsigned* cursor, const unsigned short* x,
    const float* ws1hT, const float* wd1hT, float* al_s1, float* al_d1) {
  int bid = blockIdx.x;
  int t = threadIdx.x;
  if (bid < S3B) {  // ---- scan3 role ----
    __shared__ unsigned pref[128];
    unsigned orig = 0u;
    if (t < 128) {
      orig = (t < NB1) ? part[t] : 0u;
      pref[t] = orig;
    }
    __syncthreads();
    for (int o = 1; o < 128; o <<= 1) {
      unsigned add = 0u;
      if (t < 128 && t >= o) add = pref[t - o];
      __syncthreads();
      if (t < 128) pref[t] += add;
      __syncthreads();
    }
    if (t < 128) pref[t] -= orig;  // exclusive
    __syncthreads();
    int i = bid * 256 + t;
    if (i < NN) {
      unsigned r = rowptr[i] + pref[i >> 10];
      rowptr[i] = r;
      cursor[i] = r;
    }
    if (i == 0) rowptr[NN] = EE;
    return;
  }
  // ---- al role: 32 nodes per block ----
  int ab = bid - S3B;
  int lane = t & 63, wid = t >> 6;
  int g = lane >> 3;         // head
  int cb = (lane & 7) * 16;  // channel base
  float wsv[16], wdv[16];
#pragma unroll
  for (int q = 0; q < 4; q++) {
    *(float4*)(wsv + q * 4) = *(const float4*)(ws1hT + g * 128 + cb + q * 4);
    *(float4*)(wdv + q * 4) = *(const float4*)(wd1hT + g * 128 + cb + q * 4);
  }
  int nodebase = ab * 32 + wid * 8;
  for (int nn = 0; nn < 8; nn++) {
    int i = nodebase + nn;
    bf16x8 xa = *(const bf16x8*)(x + (size_t)i * 128 + cb);
    bf16x8 xb = *(const bf16x8*)(x + (size_t)i * 128 + cb + 8);
    float s = 0.f, d = 0.f;
#pragma unroll
    for (int q = 0; q < 8; q++) {
      float xv = bf2f((unsigned short)xa[q]);
      s = fmaf(xv, wsv[q], s);
      d = fmaf(xv, wdv[q], d);
    }
#pragma unroll
    for (int q = 0; q < 8; q++) {
      float xv = bf2f((unsigned short)xb[q]);
      s = fmaf(xv, wsv[8 + q], s);
      d = fmaf(xv, wdv[8 + q], d);
    }
    s += __shfl_xor(s, 1); s += __shfl_xor(s, 2); s += __shfl_xor(s, 4);
    d += __shfl_xor(d, 1); d += __shfl_xor(d, 2); d += __shfl_xor(d, 4);
    if ((lane & 7) == 0) {
      al_s1[i * 8 + g] = s;
      al_d1[i * 8 + g] = d;
    }
  }
}

// ---------- F2: gemm1 (MFMA) ∥ scatter (32B PEdge records), role-interleaved ----------
__global__ __launch_bounds__(256) void k_fuse2(
    const unsigned short* x, const unsigned short* W1t, unsigned short* xw1,
    const int* src, const int* dst, const float* ea, const float* V1, const float* V2,
    unsigned* cursor, PEdge* ep) {
  __shared__ char wlds[65536];
  int bid = blockIdx.x;
  if (bid % 6 == 0) {  // ---- gemm1 role (bid/6 in [0, GB1)) ----
    int gb = bid / 6;
    int tid = threadIdx.x;
#pragma unroll
    for (int it = 0; it < 16; it++) {
      int cch = it * 256 + tid;
      int row = cch >> 4, seg = cch & 15;
      uint4 v = *(const uint4*)(W1t + row * 128 + seg * 8);
      *(uint4*)(&wlds[(row * 256 + seg * 16) ^ ((row & 7) << 4)]) = v;
    }
    __syncthreads();
    int wid = tid >> 6, l = tid & 63;
    int cl = l & 15, kh = l >> 4;
    int swz = (cl & 7) << 4;
    long r0 = (long)gb * 128 + wid * 32;
    f32x4 acc[2][16];
#pragma unroll
    for (int rt = 0; rt < 2; rt++)
#pragma unroll
      for (int nt = 0; nt < 16; nt++) acc[rt][nt] = {0.f, 0.f, 0.f, 0.f};
    long ra0 = r0 + cl; if (ra0 > NN - 1) ra0 = NN - 1;
    long ra1 = r0 + 16 + cl; if (ra1 > NN - 1) ra1 = NN - 1;
#pragma unroll
    for (int kk = 0; kk < 4; kk++) {
      bf16x8 a0 = *(const bf16x8*)(x + ra0 * 128 + kk * 32 + kh * 8);
      bf16x8 a1 = *(const bf16x8*)(x + ra1 * 128 + kk * 32 + kh * 8);
#pragma unroll
      for (int nt = 0; nt < 16; nt++) {
        bf16x8 b = *(const bf16x8*)(&wlds[(((nt * 16 + cl) * 256) + kk * 64 + kh * 16) ^ swz]);
        acc[0][nt] = __builtin_amdgcn_mfma_f32_16x16x32_bf16(a0, b, acc[0][nt], 0, 0, 0);
        acc[1][nt] = __builtin_amdgcn_mfma_f32_16x16x32_bf16(a1, b, acc[1][nt], 0, 0, 0);
      }
    }
#pragma unroll
    for (int rt = 0; rt < 2; rt++)
#pragma unroll
      for (int nt = 0; nt < 16; nt++)
#pragma unroll
        for (int j = 0; j < 4; j++) {
          long row = r0 + rt * 16 + kh * 4 + j;
          if (row < NN) xw1[row * 256 + nt * 16 + cl] = f2bf(acc[rt][nt][j]);
        }
  } else {  // ---- scatter role ----
    int sidx = bid - bid / 6 - 1;
    int e = sidx * 256 + threadIdx.x;
    if (e >= EE) return;
    int d = dst[e];
    unsigned pos = atomicAdd(&cursor[d], 1u);
    float av[5];
#pragma unroll
    for (int k = 0; k < 5; k++) av[k] = ea[(size_t)e * 5 + k];
    float a2 = 0.f;
#pragma unroll
    for (int k = 0; k < 5; k++) a2 = fmaf(av[k], V2[k], a2);
    unsigned short hb[8];
#pragma unroll
    for (int hh = 0; hh < 8; hh++) {
      float a1 = 0.f;
#pragma unroll
      for (int k = 0; k < 5; k++) a1 = fmaf(av[k], V1[k * 8 + hh], a1);
      hb[hh] = f2h(a1);
    }
    uint4 w0, w1;
    w0.x = (unsigned)src[e];
    w0.y = __float_as_uint(a2);
    w0.z = (unsigned)hb[0] | ((unsigned)hb[1] << 16);
    w0.w = (unsigned)hb[2] | ((unsigned)hb[3] << 16);
    w1.x = (unsigned)hb[4] | ((unsigned)hb[5] << 16);
    w1.y = (unsigned)hb[6] | ((unsigned)hb[7] << 16);
    w1.z = 0u; w1.w = 0u;
    uint4* p = (uint4*)(ep + pos);
    p[0] = w0;
    p[1] = w1;
  }
}

// ---------- K5: MFMA xw2(bf16) = h(bf16)@W2 [N,128] ----------
__global__ __launch_bounds__(256) void k_gemm2(const unsigned short* h,
                                               const unsigned short* W2t,
                                               unsigned short* xw2) {
  __shared__ char wlds[65536];
  int tid = threadIdx.x;
#pragma unroll
  for (int it = 0; it < 16; it++) {
    int cch = it * 256 + tid;
    int row = cch >> 5, seg = cch & 31;
    uint4 v = *(const uint4*)(W2t + row * 256 + seg * 8);
    *(uint4*)(&wlds[(row * 512 + seg * 16) ^ ((row & 7) << 4)]) = v;
  }
  __syncthreads();
  int wid = tid >> 6, l = tid & 63;
  int cl = l & 15, kh = l >> 4;
  int swz = (cl & 7) << 4;
  long r0 = (long)blockIdx.x * 128 + wid * 32;
  f32x4 acc[2][8];
#pragma unroll
  for (int rt = 0; rt < 2; rt++)
#pragma unroll
    for (int nt = 0; nt < 8; nt++) acc[rt][nt] = {0.f, 0.f, 0.f, 0.f};
  long ra0 = r0 + cl; if (ra0 > NN - 1) ra0 = NN - 1;
  long ra1 = r0 + 16 + cl; if (ra1 > NN - 1) ra1 = NN - 1;
#pragma unroll
  for (int kk = 0; kk < 8; kk++) {
    bf16x8 a0 = *(const bf16x8*)(h + ra0 * 256 + kk * 32 + kh * 8);
    bf16x8 a1 = *(const bf16x8*)(h + ra1 * 256 + kk * 32 + kh * 8);
#pragma unroll
    for (int nt = 0; nt < 8; nt++) {
      bf16x8 b = *(const bf16x8*)(&wlds[(((nt * 16 + cl) * 512) + kk * 64 + kh * 16) ^ swz]);
      acc[0][nt] = __builtin_amdgcn_mfma_f32_16x16x32_bf16(a0, b, acc[0][nt], 0, 0, 0);
      acc[1][nt] = __builtin_amdgcn_mfma_f32_16x16x32_bf16(a1, b, acc[1][nt], 0, 0, 0);
    }
  }
#pragma unroll
  for (int rt = 0; rt < 2; rt++)
#pragma unroll
    for (int nt = 0; nt < 8; nt++)
#pragma unroll
      for (int j = 0; j < 4; j++) {
        long row = r0 + rt * 16 + kh * 4 + j;
        if (row < NN) xw2[row * 128 + nt * 16 + cl] = f2bf(acc[rt][nt][j]);
      }
}

// ---------- K4: layer-1 GAT, wave per dst node, 16-edge double-chunk softmax ----------
__global__ __launch_bounds__(256) void k_gat1(
    const unsigned* rowptr, const PEdge* ep, const float* al_s1, const float* al_d1,
    const unsigned short* xw1, const float* b1, const float* us2, const float* ud2,
    unsigned short* h, float* al_s2, float* al_d2) {
  int w = threadIdx.x >> 6, lane = threadIdx.x & 63;
  int i = blockIdx.x * 4 + w;
  if (i >= NN) return;
  int r0 = rowptr[i], r1 = rowptr[i + 1];
  int hh = lane & 7;   // head (pass A)
  int js = lane >> 3;  // edge-sub (pass A)
  int ah = lane >> 3;  // head owning channels lane*4..lane*4+3 (pass B)
  float ald = al_d1[i * 8 + hh];
  float m = -1e30f, l = 0.f;
  float a0 = 0.f, a1 = 0.f, a2 = 0.f, a3 = 0.f;
  float alesum = 0.f;

  auto chunk16 = [&](int jb) {  // exactly 16 edges
    int jc0 = jb + js, jc1 = jb + 8 + js;
    int s0 = ((const int*)&ep[jc0])[0];
    int s1 = ((const int*)&ep[jc1])[0];
    float e0 = h2f(((const unsigned short*)&ep[jc0])[4 + hh]);
    float e1 = h2f(((const unsigned short*)&ep[jc1])[4 + hh]);
    alesum += e0 + e1;
    float g0 = al_s1[s0 * 8 + hh] + ald + e0;
    g0 = g0 > 0.f ? g0 : 0.2f * g0;
    float g1 = al_s1[s1 * 8 + hh] + ald + e1;
    g1 = g1 > 0.f ? g1 : 0.2f * g1;
    float cm = fmaxf(g0, g1);
    cm = fmaxf(cm, __shfl_xor(cm, 8));
    cm = fmaxf(cm, __shfl_xor(cm, 16));
    cm = fmaxf(cm, __shfl_xor(cm, 32));
    float mn = fmaxf(m, cm);
    float sc = exp2f(m - mn);
    float p0 = exp2f(g0 - mn), p1 = exp2f(g1 - mn);
    float ps = p0 + p1;
    ps += __shfl_xor(ps, 8);
    ps += __shfl_xor(ps, 16);
    ps += __shfl_xor(ps, 32);
    l = l * sc + ps;
    m = mn;
    float asc = __shfl(sc, ah);
    a0 *= asc; a1 *= asc; a2 *= asc; a3 *= asc;
#pragma unroll
    for (int jj = 0; jj < 8; jj++) {
      float pj = __shfl(p0, jj * 8 + ah);
      int sj = __shfl(s0, jj * 8);
      ushort4 xv = ((const ushort4*)(xw1 + (size_t)sj * 256))[lane];
      a0 = fmaf(pj, bf2f(xv.x), a0);
      a1 = fmaf(pj, bf2f(xv.y), a1);
      a2 = fmaf(pj, bf2f(xv.z), a2);
      a3 = fmaf(pj, bf2f(xv.w), a3);
    }
#pragma unroll
    for (int jj = 0; jj < 8; jj++) {
      float pj = __shfl(p1, jj * 8 + ah);
      int sj = __shfl(s1, jj * 8);
      ushort4 xv = ((const ushort4*)(xw1 + (size_t)sj * 256))[lane];
      a0 = fmaf(pj, bf2f(xv.x), a0);
      a1 = fmaf(pj, bf2f(xv.y), a1);
      a2 = fmaf(pj, bf2f(xv.z), a2);
      a3 = fmaf(pj, bf2f(xv.w), a3);
    }
  };

  auto chunk8 = [&](int jb, int cnt) {  // 1..8 edges
    bool valid = js < cnt;
    int jc = jb + (valid ? js : cnt - 1);
    int s = ((const int*)&ep[jc])[0];
    float ale = h2f(((const unsigned short*)&ep[jc])[4 + hh]);
    if (!valid) ale = 0.f;
    alesum += ale;
    float logit = -1e30f;
    if (valid) {
      float al = al_s1[s * 8 + hh] + ald + ale;
      logit = al > 0.f ? al : 0.2f * al;
    }
    float cm = logit;
    cm = fmaxf(cm, __shfl_xor(cm, 8));
    cm = fmaxf(cm, __shfl_xor(cm, 16));
    cm = fmaxf(cm, __shfl_xor(cm, 32));
    float mn = fmaxf(m, cm);
    float sc = exp2f(m - mn);
    float p = exp2f(logit - mn);
    float ps = p;
    ps += __shfl_xor(ps, 8);
    ps += __shfl_xor(ps, 16);
    ps += __shfl_xor(ps, 32);
    l = l * sc + ps;
    m = mn;
    float asc = __shfl(sc, ah);
    a0 *= asc; a1 *= asc; a2 *= asc; a3 *= asc;
    for (int jj = 0; jj < cnt; jj++) {
      float pj = __shfl(p, jj * 8 + ah);
      int sj = __shfl(s, jj * 8);
      ushort4 xv = ((const ushort4*)(xw1 + (size_t)sj * 256))[lane];
      a0 = fmaf(pj, bf2f(xv.x), a0);
      a1 = fmaf(pj, bf2f(xv.y), a1);
      a2 = fmaf(pj, bf2f(xv.z), a2);
      a3 = fmaf(pj, bf2f(xv.w), a3);
    }
  };

  int jb = r0;
  for (; jb + 16 <= r1; jb += 16) chunk16(jb);
  if (jb + 8 <= r1) { chunk8(jb, 8); jb += 8; }
  if (jb < r1) chunk8(jb, r1 - jb);

  // self-loop (edge_attr = mean of incoming per-edge ale, by linearity)
  alesum += __shfl_xor(alesum, 8);
  alesum += __shfl_xor(alesum, 16);
  alesum += __shfl_xor(alesum, 32);
  float inv = 1.f / fmaxf((float)(r1 - r0), 1.f);
  float aleS = alesum * inv;
  {
    float al = al_s1[i * 8 + hh] + ald + aleS;
    float logit = al > 0.f ? al : 0.2f * al;
    float mn = fmaxf(m, logit);
    float sc = exp2f(m - mn);
    float p = exp2f(logit - mn);
    l = l * sc + p;
    m = mn;
    float asc = __shfl(sc, ah);
    float pj = __shfl(p, ah);
    ushort4 xv = ((const ushort4*)(xw1 + (size_t)i * 256))[lane];
    a0 = fmaf(pj, bf2f(xv.x), a0 * asc);
    a1 = fmaf(pj, bf2f(xv.y), a1 * asc);
    a2 = fmaf(pj, bf2f(xv.z), a2 * asc);
    a3 = fmaf(pj, bf2f(xv.w), a3 * asc);
  }
  // finalize: /l + b1, elu
  float lh = __shfl(l, ah);
  float invl = 1.f / (lh + 1e-16f);
  float4 bv = ((const float4*)b1)[lane];
  float v0 = a0 * invl + bv.x, v1 = a1 * invl + bv.y;
  float v2 = a2 * invl + bv.z, v3 = a3 * invl + bv.w;
  v0 = v0 > 0.f ? v0 : expm1f(v0);
  v1 = v1 > 0.f ? v1 : expm1f(v1);
  v2 = v2 > 0.f ? v2 : expm1f(v2);
  v3 = v3 > 0.f ? v3 : expm1f(v3);
  ushort4 hv;
  hv.x = f2bf(v0); hv.y = f2bf(v1); hv.z = f2bf(v2); hv.w = f2bf(v3);
  ((ushort4*)(h + (size_t)i * 256))[lane] = hv;
  // layer-2 logit pieces (us2/ud2 pre-scaled by log2e)
  float4 uv = ((const float4*)us2)[lane];
  float4 dv = ((const float4*)ud2)[lane];
  float ps2 = v0 * uv.x + v1 * uv.y + v2 * uv.z + v3 * uv.w;
  float pd2 = v0 * dv.x + v1 * dv.y + v2 * dv.z + v3 * dv.w;
  ps2 = wave_sum(ps2);
  pd2 = wave_sum(pd2);
  if (lane == 0) { al_s2[i] = ps2; al_d2[i] = pd2; }
}

// ---------- K6: layer-2 GAT, wave per dst node, two-phase softmax (low-VGPR) ----------
__global__ __launch_bounds__(256) void k_gat2(
    const unsigned* rowptr, const PEdge* ep, const float* al_s2, const float* al_d2,
    const unsigned short* xw2, const float* b2, float* out) {
  int w = threadIdx.x >> 6, lane = threadIdx.x & 63;
  int i = blockIdx.x * 4 + w;
  if (i >= NN) return;
  int r0 = rowptr[i], r1 = rowptr[i + 1];
  float ald = al_d2[i];
  float m = -1e30f, l = 0.f, a0 = 0.f, a1 = 0.f;
  float alesum = 0.f;

  auto chunk = [&](int jb, int cnt) {  // 1..64 edges
    bool valid = lane < cnt;
    int jc = jb + (valid ? lane : cnt - 1);
    int2 sv = *(const int2*)&ep[jc];
    int s = sv.x;
    float ale = valid ? __uint_as_float((unsigned)sv.y) : 0.f;
    alesum += ale;
    float logit = -1e30f;
    if (valid) {
      float al = al_s2[s] + ald + ale;
      logit = al > 0.f ? al : 0.2f * al;
    }
    float cm = wave_max(logit);
    float mn = fmaxf(m, cm);
    float sc = exp2f(m - mn);
    float p = exp2f(logit - mn);
    float ps = wave_sum(p);
    l = l * sc + ps;
    m = mn;
    a0 *= sc; a1 *= sc;
    for (int jj = 0; jj < cnt; jj++) {
      float pj = __shfl(p, jj);
      int sj = __shfl(s, jj);
      ushort2 xv = ((const ushort2*)(xw2 + (size_t)sj * 128))[lane];
      a0 = fmaf(pj, bf2f(xv.x), a0);
      a1 = fmaf(pj, bf2f(xv.y), a1);
    }
  };
  int jb = r0;
  for (; jb + 64 <= r1; jb += 64) chunk(jb, 64);
  if (jb < r1) chunk(jb, r1 - jb);

  // self-loop
  alesum = wave_sum(alesum);
  float inv = 1.f / fmaxf((float)(r1 - r0), 1.f);
  float aleS = alesum * inv;
  {
    float al = al_s2[i] + ald + aleS;
    float logit = al > 0.f ? al : 0.2f * al;
    float mn = fmaxf(m, logit);
    float sc = exp2f(m - mn);
    float p = exp2f(logit - mn);
    l = l * sc + p;
    ushort2 xv = ((const ushort2*)(xw2 + (size_t)i * 128))[lane];
    a0 = fmaf(p, bf2f(xv.x), a0 * sc);
    a1 = fmaf(p, bf2f(xv.y), a1 * sc);
  }
  float invl = 1.f / (l + 1e-16f);
  float2 bv = ((const float2*)b2)[lane];
  float2 ov = {a0 * invl + bv.x, a1 * invl + bv.y};
  ((float2*)(out + (size_t)i * 128))[lane] = ov;
}

extern "C" void kernel_launch(void* const* d_in, const int* in_sizes, int n_in,
                              void* d_out, int out_size, void* d_ws, size_t ws_size,
                              hipStream_t stream) {
  const float* pol_feat = (const float*)d_in[0];
  const int* state_ids = (const int*)d_in[1];
  const int* comp_cat = (const int*)d_in[2];
  const float* comp_price = (const float*)d_in[3];
  const int* edge_index = (const int*)d_in[4];
  const float* edge_attr = (const float*)d_in[5];
  const float* Wp = (const float*)d_in[6];
  const float* bp = (const float*)d_in[7];
  const float* state_emb = (const float*)d_in[8];
  const float* sector_emb = (const float*)d_in[9];
  const float* industry_emb = (const float*)d_in[10];
  const float* Wc = (const float*)d_in[11];
  const float* bc = (const float*)d_in[12];
  const float* ln_g = (const float*)d_in[13];
  const float* ln_b = (const float*)d_in[14];
  const float* W1 = (const float*)d_in[15];
  const float* as1 = (const float*)d_in[16];
  const float* ad1 = (const float*)d_in[17];
  const float* We1 = (const float*)d_in[18];
  const float* ae1 = (const float*)d_in[19];
  const float* b1 = (const float*)d_in[20];
  const float* W2 = (const float*)d_in[21];
  const float* as2 = (const float*)d_in[22];
  const float* ad2 = (const float*)d_in[23];
  const float* We2 = (const float*)d_in[24];
  const float* ae2 = (const float*)d_in[25];
  const float* b2 = (const float*)d_in[26];
  const int* srcv = edge_index;
  const int* dstv = edge_index + EE;
  float* out = (float*)d_out;

  // ---- workspace layout (aliased; peak ~143 MiB) ----
  size_t off = 0;
  auto alloc = [&](size_t nbytes) -> char* {
    char* p = (char*)d_ws + off;
    off += ((nbytes + 255) & ~(size_t)255);
    return p;
  };
  // region A: xw1 (bf16, NN*256*2); xw2 (bf16, NN*128*2) reuses it after gat1
  char* regA = alloc((size_t)NN * 512);
  // region B: h (bf16, NN*256*2); x (bf16, NN*128*2) occupies first half (dead after gemm1)
  char* regB = alloc((size_t)NN * 512);
  unsigned short* xw1 = (unsigned short*)regA;
  unsigned short* xw2 = (unsigned short*)regA;
  unsigned short* h = (unsigned short*)regB;
  unsigned short* x = (unsigned short*)regB;
  float* al_s1 = (float*)alloc((size_t)NN * 8 * 4);
  float* al_d1 = (float*)alloc((size_t)NN * 8 * 4);
  float* al_s2 = (float*)alloc((size_t)NN * 4);
  float* al_d2 = (float*)alloc((size_t)NN * 4);
  float* us2 = (float*)alloc(256 * 4);
  float* ud2 = (float*)alloc(256 * 4);
  float* V1 = (float*)alloc(64 * 4);
  float* V2 = (float*)alloc(8 * 4);
  float* Ts = (float*)alloc(16 * 128 * 4);
  float* Ti = (float*)alloc(150 * 128 * 4);
  float* ws1hT = (float*)alloc(1024 * 4);
  float* wd1hT = (float*)alloc(1024 * 4);
  unsigned short* W1t = (unsigned short*)alloc(32768 * 2);
  unsigned short* W2t = (unsigned short*)alloc(32768 * 2);
  unsigned* hist = (unsigned*)alloc((size_t)NN * 4);
  unsigned* rowptr = (unsigned*)alloc((size_t)(NN + 1) * 4);
  unsigned* cursor = (unsigned*)alloc((size_t)NN * 4);
  unsigned* part = (unsigned*)alloc((size_t)NB1 * 4);
  PEdge* ep = (PEdge*)alloc((size_t)EE * sizeof(PEdge));

  hipMemsetAsync(hist, 0, (size_t)NN * 4, stream);

  k_fuse1<<<PB + SB, 256, 0, stream>>>(W1, W2, as2, ad2, We1, ae1, We2, ae2,
                                       sector_emb, industry_emb, Wc, as1, ad1, dstv,
                                       W1t, W2t, Ts, Ti, us2, ud2, V1, V2, ws1hT,
                                       wd1hT, hist);
  k_fuse_es<<<NB1 + NN / 2, 256, 0, stream>>>(hist, rowptr, part, pol_feat, state_ids,
                                              comp_cat, comp_price, Wp, bp, state_emb,
                                              Ts, Ti, Wc, bc, ln_g, ln_b, x);
  k_scan3_al<<<S3B + AB, 256, 0, stream>>>(rowptr, part, cursor, x, ws1hT, wd1hT,
                                           al_s1, al_d1);
  k_fuse2<<<GB1 * 6 + (SB - GB1 * 5), 256, 0, stream>>>(x, W1t, xw1, srcv, dstv,
                                                        edge_attr, V1, V2, cursor, ep);
  k_gat1<<<NN / 4, 256, 0, stream>>>(rowptr, ep, al_s1, al_d1, xw1, b1, us2, ud2, h,
                                     al_s2, al_d2);
  k_gemm2<<<(NN + 127) / 128, 256, 0, stream>>>(h, W2t, xw2);
  k_gat2<<<NN / 4, 256, 0, stream>>>(rowptr, ep, al_s2, al_d2, xw2, b2, out);
}